// Round 21
// baseline (160.655 us; speedup 1.0000x reference)
//
#include <hip/hip_runtime.h>

typedef unsigned short u16;
typedef unsigned int   u32;
typedef __attribute__((ext_vector_type(8))) short short8;
typedef __attribute__((ext_vector_type(4))) unsigned int u32x4;
typedef __attribute__((ext_vector_type(4))) float f32x4;

__device__ __forceinline__ u16 f2b(float f) {
    u32 u = __float_as_uint(f);
    u32 r = (u + 0x7fffu + ((u >> 16) & 1u)) >> 16;   // round-to-nearest-even
    return (u16)r;
}
__device__ __forceinline__ float blo(u32 w) { return __uint_as_float(w << 16); }
__device__ __forceinline__ float bhi(u32 w) { return __uint_as_float(w & 0xffff0000u); }

// ---------------- prep: MtB | w0s/w0d | edge->bin fill (r16 layout — fill here, NOT in k_pre;
// r19 showed the overlap attempt serializes and costs ~7 µs) ----------------
__global__ void k_prep(const float* __restrict__ Wq, const float* __restrict__ Wk, u16* __restrict__ MtB,
                       const float* __restrict__ W0,
                       const float* __restrict__ asrc, const float* __restrict__ adst,
                       float* __restrict__ w0s, float* __restrict__ w0d,
                       const int* __restrict__ src, const int* __restrict__ dst,
                       int* __restrict__ cnt, int* __restrict__ cs, int E) {
    int b = blockIdx.x, t = threadIdx.x;
    if (b < 64) {
        int id = b * 256 + t;                  // [0, 16384)
        int bcol = id >> 7, a = id & 127;
        const float* wqr = Wq + a * 128;
        const float* wkr = Wk + bcol * 128;
        float dt = 0.f;
        for (int j = 0; j < 128; j += 4) {
            float4 q4 = *reinterpret_cast<const float4*>(wqr + j);
            float4 k4 = *reinterpret_cast<const float4*>(wkr + j);
            dt += q4.x * k4.x + q4.y * k4.y + q4.z * k4.z + q4.w * k4.w;
        }
        MtB[id] = f2b(dt * 0.08838834764831845f);
    } else if (b == 64) {
        int k = t & 127;
        const float* av = (t < 128) ? asrc : adst;
        const float* wr = W0 + k * 128;
        float dt = 0.f;
        for (int j = 0; j < 128; j += 4) {
            float4 w4 = *reinterpret_cast<const float4*>(wr + j);
            float4 a4 = *reinterpret_cast<const float4*>(av + j);
            dt += w4.x * a4.x + w4.y * a4.y + w4.z * a4.z + w4.w * a4.w;
        }
        if (t < 128) w0s[k] = dt; else w0d[k] = dt;
    } else {
        int e = (b - 65) * 256 + t;
        if (e < E) {
            int d = dst[e];
            int slot = atomicAdd(&cnt[d], 1);
            if (slot < 32) cs[(size_t)d * 32 + slot] = src[e];
        }
    }
}

// ---------------- pre-GEMM: fp32 X -> Xb (bf16) + Q' = X@M + a_s/a_d ; + Wf prep blocks ----
__global__ __launch_bounds__(512) void k_pre(const float* __restrict__ X, u16* __restrict__ Xb,
                                             const u16* __restrict__ MtB,
                                             const float* __restrict__ w0s, const float* __restrict__ w0d,
                                             const float* __restrict__ W0, const float* __restrict__ Wv,
                                             const float* __restrict__ Wr, u16* __restrict__ Wf,
                                             u16* __restrict__ Qp, float* __restrict__ a_s,
                                             float* __restrict__ a_d, int N, int nxb) {
    const int tid = threadIdx.x;
    if ((int)blockIdx.x >= nxb) {
        // Wf fragment order: chunk = ((g*4+w)*2+p)*4+kc ; lane l elem i:
        //   col = w*32 + 2*(l&15) + p ; k = kc*32 + (l>>4)*8 + i ; value = W_g[k][col]
        int id = ((int)blockIdx.x - nxb) * 512 + tid;   // [0, 49152)
        int i = id & 7, l = (id >> 3) & 63, chunk = id >> 9;
        int kc = chunk & 3, p = (chunk >> 2) & 1, wv = (chunk >> 3) & 3, g = chunk >> 5;
        int col = wv * 32 + 2 * (l & 15) + p;
        int k = kc * 32 + (l >> 4) * 8 + i;
        const float* W = g == 0 ? W0 : g == 1 ? Wv : Wr;
        Wf[id] = f2b(W[k * 128 + col]);
        return;
    }

    __shared__ u16 Bs[128][136];
    const int row0 = blockIdx.x * 128;

    for (int c = tid; c < 128 * 16; c += 512) {
        int r = c >> 4, col8 = (c & 15) * 8;
        *reinterpret_cast<short8*>(&Bs[r][col8]) =
            *reinterpret_cast<const short8*>(MtB + r * 128 + col8);
    }

    const int wid = tid >> 6, lane = tid & 63;
    const int l15 = lane & 15;
    const int kg = (lane >> 4) * 8;
    const int arow = row0 + wid * 16 + l15;

    short8 af[4];
    if (arow < N) {
        const float* xp = X + (size_t)arow * 128 + kg;
        u16* xbp = Xb + (size_t)arow * 128 + kg;
#pragma unroll
        for (int kc = 0; kc < 4; kc++) {
            float4 f0 = *reinterpret_cast<const float4*>(xp + kc * 32);
            float4 f1 = *reinterpret_cast<const float4*>(xp + kc * 32 + 4);
            short8 vv;
            vv[0] = (short)f2b(f0.x); vv[1] = (short)f2b(f0.y);
            vv[2] = (short)f2b(f0.z); vv[3] = (short)f2b(f0.w);
            vv[4] = (short)f2b(f1.x); vv[5] = (short)f2b(f1.y);
            vv[6] = (short)f2b(f1.z); vv[7] = (short)f2b(f1.w);
            af[kc] = vv;
            *reinterpret_cast<short8*>(xbp + kc * 32) = vv;
        }
    } else {
        short8 z = {0, 0, 0, 0, 0, 0, 0, 0};
#pragma unroll
        for (int kc = 0; kc < 4; kc++) af[kc] = z;
    }
    __syncthreads();

    float ps = 0.f, pd = 0.f;
#pragma unroll
    for (int kc = 0; kc < 4; kc++) {
        float4 s0 = *reinterpret_cast<const float4*>(w0s + kc * 32 + kg);
        float4 s1 = *reinterpret_cast<const float4*>(w0s + kc * 32 + kg + 4);
        float4 d0 = *reinterpret_cast<const float4*>(w0d + kc * 32 + kg);
        float4 d1 = *reinterpret_cast<const float4*>(w0d + kc * 32 + kg + 4);
        float xs[8];
#pragma unroll
        for (int i = 0; i < 8; i++) xs[i] = __uint_as_float(((u32)(u16)af[kc][i]) << 16);
        ps += xs[0] * s0.x + xs[1] * s0.y + xs[2] * s0.z + xs[3] * s0.w
            + xs[4] * s1.x + xs[5] * s1.y + xs[6] * s1.z + xs[7] * s1.w;
        pd += xs[0] * d0.x + xs[1] * d0.y + xs[2] * d0.z + xs[3] * d0.w
            + xs[4] * d1.x + xs[5] * d1.y + xs[6] * d1.z + xs[7] * d1.w;
    }
    ps += __shfl_xor(ps, 16); ps += __shfl_xor(ps, 32);
    pd += __shfl_xor(pd, 16); pd += __shfl_xor(pd, 32);
    if (lane < 16 && arow < N) { a_s[arow] = ps; a_d[arow] = pd; }

    const int rbase = row0 + wid * 16 + ((lane >> 4) << 2);

#pragma unroll
    for (int c2 = 0; c2 < 4; c2++) {
        const int col0 = c2 * 32 + 2 * l15;
        f32x4 acc0 = {0.f, 0.f, 0.f, 0.f};
        f32x4 acc1 = {0.f, 0.f, 0.f, 0.f};
#pragma unroll
        for (int kc = 0; kc < 4; kc++) {
            short8 bf0 = *reinterpret_cast<const short8*>(&Bs[col0][kc * 32 + kg]);
            short8 bf1 = *reinterpret_cast<const short8*>(&Bs[col0 + 1][kc * 32 + kg]);
            acc0 = __builtin_amdgcn_mfma_f32_16x16x32_bf16(af[kc], bf0, acc0, 0, 0, 0);
            acc1 = __builtin_amdgcn_mfma_f32_16x16x32_bf16(af[kc], bf1, acc1, 0, 0, 0);
        }
#pragma unroll
        for (int r = 0; r < 4; r++) {
            int grow = rbase + r;
            if (grow < N) {
                u32 pk = (u32)f2b(acc0[r]) | ((u32)f2b(acc1[r]) << 16);
                *reinterpret_cast<u32*>(Qp + (size_t)grow * 128 + col0) = pk;
            }
        }
    }
}

// ---------------- fused edge + post: 32 nodes/block, SEQUENTIAL pairs ----------------
// Phase A: each 16-lane group runs TWO nodes back-to-back (pair work ~ Poisson(12);
// barrier waits max-of-16-pairs ≈ 1.6x mean vs 2.0x for singles) — no extra registers
// (r13's VGPR failure mode avoided by sequencing, not widening). Phase B: tt=0,1
// sequentially, same accumulator registers, Wf re-fetched from hot L2 per tt.
// No max-subtraction (validated r1-r19).
__global__ __launch_bounds__(256) void k_edge(const int* __restrict__ cnt, const int* __restrict__ cs,
                                              const u16* __restrict__ Xb, const u16* __restrict__ Qp,
                                              const float* __restrict__ a_s, const float* __restrict__ a_d,
                                              const u16* __restrict__ Wf, const float* __restrict__ bias,
                                              float* __restrict__ out,
                                              const int* __restrict__ srcp, const int* __restrict__ dstp,
                                              int E, int N) {
    __shared__ u16 As[3][32][136];   // [ax|bx|x][node][col] (+8 pad)
    __shared__ float ssp[4][32];     // per-wave row-norm partials (both tiles)
    const int tid = threadIdx.x;
    const int node0 = blockIdx.x * 32;
    const int g16 = tid >> 4;
    const int l = tid & 15;
    const int l8 = l * 8;

    // ---------------- phase A: two nodes, sequential ----------------
#pragma unroll 1
    for (int tt = 0; tt < 2; tt++) {
        const int row = tt * 16 + g16;
        const int n = node0 + row;
        if (n < N) {
            u32x4 qv = *reinterpret_cast<const u32x4*>(Qp + (size_t)n * 128 + l8);
            short8 selfx = *reinterpret_cast<const short8*>(Xb + ((size_t)n << 7) + l8);
            float qf[8];
#pragma unroll
            for (int i = 0; i < 4; i++) { qf[2 * i] = blo(qv[i]); qf[2 * i + 1] = bhi(qv[i]); }

            const int deg = cnt[n];
            const int binb = n * 32;
            const float adn = a_d[n];

            float axr[8] = {0.f, 0.f, 0.f, 0.f, 0.f, 0.f, 0.f, 0.f};
            float bxr[8] = {0.f, 0.f, 0.f, 0.f, 0.f, 0.f, 0.f, 0.f};
            float zg = 0.f, zt = 0.f;

            if (deg <= 32) {
                const int m = deg < 16 ? deg : 16;
                int sx_l = 0;
                float wg_l = 0.f;
                if (l < m) {
                    int s = cs[binb + l];
                    float gl = a_s[s] + adn;
                    gl = gl >= 0.f ? gl : 0.2f * gl;  // LeakyReLU(0.2)
                    wg_l = __expf(gl);
                    sx_l = s << 7;
                }
                for (int j = 0; j < m; j++) {
                    int ex0 = __shfl(sx_l, j, 16);
                    float wg0 = __shfl(wg_l, j, 16);
                    u32x4 xv = *reinterpret_cast<const u32x4*>(Xb + ex0 + l8);

                    float d0 = 0.f;
#pragma unroll
                    for (int i = 0; i < 4; i++) {
                        d0 = fmaf(qf[2 * i], blo(xv[i]), d0);
                        d0 = fmaf(qf[2 * i + 1], bhi(xv[i]), d0);
                    }
                    d0 += __shfl_xor(d0, 1);
                    d0 += __shfl_xor(d0, 2);
                    d0 += __shfl_xor(d0, 4);
                    d0 += __shfl_xor(d0, 8);
                    float wt0 = __expf(d0);           // 1/sqrt(D) folded into M

#pragma unroll
                    for (int i = 0; i < 4; i++) {
                        float x0 = blo(xv[i]), x1 = bhi(xv[i]);
                        axr[2 * i]     = fmaf(wg0, x0, axr[2 * i]);
                        axr[2 * i + 1] = fmaf(wg0, x1, axr[2 * i + 1]);
                        bxr[2 * i]     = fmaf(wt0, x0, bxr[2 * i]);
                        bxr[2 * i + 1] = fmaf(wt0, x1, bxr[2 * i + 1]);
                    }
                    zg += wg0;
                    zt += wt0;
                }
                for (int p = 16; p < deg; p++) {      // 16 < deg <= 32
                    int s = cs[binb + p];
                    float gl = a_s[s] + adn;
                    gl = gl >= 0.f ? gl : 0.2f * gl;
                    float wg0 = __expf(gl);
                    u32x4 xv = *reinterpret_cast<const u32x4*>(Xb + (s << 7) + l8);
                    float d0 = 0.f;
#pragma unroll
                    for (int i = 0; i < 4; i++) {
                        d0 = fmaf(qf[2 * i], blo(xv[i]), d0);
                        d0 = fmaf(qf[2 * i + 1], bhi(xv[i]), d0);
                    }
#pragma unroll
                    for (int off = 1; off < 16; off <<= 1) d0 += __shfl_xor(d0, off);
                    float wt0 = __expf(d0);
#pragma unroll
                    for (int i = 0; i < 4; i++) {
                        float x0 = blo(xv[i]), x1 = bhi(xv[i]);
                        axr[2 * i]     = fmaf(wg0, x0, axr[2 * i]);
                        axr[2 * i + 1] = fmaf(wg0, x1, axr[2 * i + 1]);
                        bxr[2 * i]     = fmaf(wt0, x0, bxr[2 * i]);
                        bxr[2 * i + 1] = fmaf(wt0, x1, bxr[2 * i + 1]);
                    }
                    zg += wg0;
                    zt += wt0;
                }
            } else {
                // correctness insurance (deg > 32, ~P=1e-15/node): full edge rescan
                for (int e = 0; e < E; e++) {
                    if (dstp[e] == n) {
                        int s = srcp[e];
                        float gl = a_s[s] + adn;
                        gl = gl >= 0.f ? gl : 0.2f * gl;
                        float wg0 = __expf(gl);
                        u32x4 xv = *reinterpret_cast<const u32x4*>(Xb + (s << 7) + l8);
                        float d0 = 0.f;
#pragma unroll
                        for (int i = 0; i < 4; i++) {
                            d0 = fmaf(qf[2 * i], blo(xv[i]), d0);
                            d0 = fmaf(qf[2 * i + 1], bhi(xv[i]), d0);
                        }
#pragma unroll
                        for (int off = 1; off < 16; off <<= 1) d0 += __shfl_xor(d0, off);
                        float wt0 = __expf(d0);
#pragma unroll
                        for (int i = 0; i < 4; i++) {
                            float x0 = blo(xv[i]), x1 = bhi(xv[i]);
                            axr[2 * i]     = fmaf(wg0, x0, axr[2 * i]);
                            axr[2 * i + 1] = fmaf(wg0, x1, axr[2 * i + 1]);
                            bxr[2 * i]     = fmaf(wt0, x0, bxr[2 * i]);
                            bxr[2 * i + 1] = fmaf(wt0, x1, bxr[2 * i + 1]);
                        }
                        zg += wg0;
                        zt += wt0;
                    }
                }
            }

            float ig = 1.f / (zg + 1e-16f), it = 1.f / (zt + 1e-16f);
            short8 pax, pbx;
#pragma unroll
            for (int i = 0; i < 8; i++) {
                pax[i] = (short)f2b(axr[i] * ig);
                pbx[i] = (short)f2b(bxr[i] * it);
            }
            *reinterpret_cast<short8*>(&As[0][row][l8]) = pax;
            *reinterpret_cast<short8*>(&As[1][row][l8]) = pbx;
            *reinterpret_cast<short8*>(&As[2][row][l8]) = selfx;
        } else {
            short8 z = {0, 0, 0, 0, 0, 0, 0, 0};
            *reinterpret_cast<short8*>(&As[0][row][l8]) = z;
            *reinterpret_cast<short8*>(&As[1][row][l8]) = z;
            *reinterpret_cast<short8*>(&As[2][row][l8]) = z;
        }
    }
    __syncthreads();

    // ---------------- phase B: two tiles, sequential (same registers) ----------------
    const int w = tid >> 6;          // wave id: cols [w*32, w*32+32)
    const int lane = tid & 63;
    const int l15 = lane & 15;
    const int q = lane >> 4;
    const int kg = q * 8;
    const int col0 = w * 32 + 2 * l15;
    const float2 bb = *reinterpret_cast<const float2*>(bias + col0);

#pragma unroll 1
    for (int tt = 0; tt < 2; tt++) {
        f32x4 aG0 = {0.f, 0.f, 0.f, 0.f}, aG1 = {0.f, 0.f, 0.f, 0.f};
        f32x4 aD0 = {0.f, 0.f, 0.f, 0.f}, aD1 = {0.f, 0.f, 0.f, 0.f};

#pragma unroll
        for (int g = 0; g < 3; g++) {
            short8 af[4];
#pragma unroll
            for (int kc = 0; kc < 4; kc++)
                af[kc] = *reinterpret_cast<const short8*>(&As[g][tt * 16 + l15][kc * 32 + kg]);
            const u16* wfg = Wf + (((g * 4 + w) * 2) << 11);
#pragma unroll
            for (int kc = 0; kc < 4; kc++) {
                short8 bf0 = *reinterpret_cast<const short8*>(wfg + kc * 512 + lane * 8);
                short8 bf1 = *reinterpret_cast<const short8*>(wfg + (4 + kc) * 512 + lane * 8);
                if (g == 0) {
                    aG0 = __builtin_amdgcn_mfma_f32_16x16x32_bf16(af[kc], bf0, aG0, 0, 0, 0);
                    aG1 = __builtin_amdgcn_mfma_f32_16x16x32_bf16(af[kc], bf1, aG1, 0, 0, 0);
                } else {
                    aD0 = __builtin_amdgcn_mfma_f32_16x16x32_bf16(af[kc], bf0, aD0, 0, 0, 0);
                    aD1 = __builtin_amdgcn_mfma_f32_16x16x32_bf16(af[kc], bf1, aD1, 0, 0, 0);
                }
            }
        }

        // epilogue for tile tt
        float o0[4], o1[4], ssr[4];
#pragma unroll
        for (int r = 0; r < 4; r++) {
            float g0 = fmaxf(aG0[r] + bb.x, 0.f);
            float g1 = fmaxf(aG1[r] + bb.y, 0.f);
            o0[r] = g0 + aD0[r];
            o1[r] = g1 + aD1[r];
            ssr[r] = o0[r] * o0[r] + o1[r] * o1[r];
        }
#pragma unroll
        for (int off = 1; off < 16; off <<= 1) {
#pragma unroll
            for (int r = 0; r < 4; r++) ssr[r] += __shfl_xor(ssr[r], off);
        }
        if (l15 == 0) {
#pragma unroll
            for (int r = 0; r < 4; r++) ssp[w][tt * 16 + q * 4 + r] = ssr[r];
        }
        __syncthreads();
#pragma unroll
        for (int r = 0; r < 4; r++) {
            int row = tt * 16 + q * 4 + r;
            float tot = ssp[0][row] + ssp[1][row] + ssp[2][row] + ssp[3][row];
            float inv = 1.f / fmaxf(sqrtf(tot), 1e-12f);
            int grow = node0 + row;
            if (grow < N) {
                float2 ov = {o0[r] * inv, o1[r] * inv};
                *reinterpret_cast<float2*>(out + (size_t)grow * 128 + col0) = ov;
            }
        }
    }
}

// ---------------- host launcher ----------------
extern "C" void kernel_launch(void* const* d_in, const int* in_sizes, int n_in,
                              void* d_out, int out_size, void* d_ws, size_t ws_size,
                              hipStream_t stream) {
    const int* edge = (const int*)d_in[1];
    const float* emb = (const float*)d_in[2];
    const float* gat_W = (const float*)d_in[3];
    const float* a_src = (const float*)d_in[4];
    const float* a_dst = (const float*)d_in[5];
    const float* bias = (const float*)d_in[6];
    const float* Wq = (const float*)d_in[7];
    const float* Wk = (const float*)d_in[8];
    const float* Wv = (const float*)d_in[9];
    const float* Wr = (const float*)d_in[10];

    const int E = in_sizes[1] / 2;
    const int N = in_sizes[2] / 128;
    const int* src = edge;
    const int* dst = edge + E;
    float* out = (float*)d_out;

    char* w = (char*)d_ws;
    auto alloc = [&](size_t bytes) -> char* {
        char* p = w;
        w += (bytes + 255) & ~(size_t)255;
        return p;
    };
    u16* Xb  = (u16*)alloc((size_t)N * 128 * 2);
    u16* Qp  = (u16*)alloc((size_t)N * 128 * 2);
    u16* MtB = (u16*)alloc(128 * 128 * 2);
    u16* Wf  = (u16*)alloc(3 * 128 * 128 * 2);
    float* w0s = (float*)alloc(128 * 4);
    float* w0d = (float*)alloc(128 * 4);
    float* a_s = (float*)alloc((size_t)N * 4);
    float* a_d = (float*)alloc((size_t)N * 4);
    int* cnt  = (int*)alloc((size_t)N * 4);
    int* cs   = (int*)alloc((size_t)N * 32 * 4);   // fixed-capacity bins (12.8 MB)

    const int nhist = (E + 255) / 256;
    const int nxb = (N + 127) / 128;

    hipMemsetAsync(cnt, 0, (size_t)N * 4, stream);
    k_prep<<<65 + nhist, 256, 0, stream>>>(Wq, Wk, MtB, gat_W, a_src, a_dst, w0s, w0d,
                                           src, dst, cnt, cs, E);
    k_pre<<<nxb + 96, 512, 0, stream>>>(emb, Xb, MtB, w0s, w0d, gat_W, Wv, Wr, Wf,
                                        Qp, a_s, a_d, N, nxb);
    k_edge<<<(N + 31) / 32, 256, 0, stream>>>(cnt, cs, Xb, Qp, a_s, a_d, Wf, bias, out,
                                              src, dst, E, N);
}

// Round 22
// 127.084 us; speedup vs baseline: 1.2642x; 1.2642x over previous
//
#include <hip/hip_runtime.h>

typedef unsigned short u16;
typedef unsigned int   u32;
typedef __attribute__((ext_vector_type(8))) short short8;
typedef __attribute__((ext_vector_type(4))) unsigned int u32x4;
typedef __attribute__((ext_vector_type(4))) float f32x4;

__device__ __forceinline__ u16 f2b(float f) {
    u32 u = __float_as_uint(f);
    u32 r = (u + 0x7fffu + ((u >> 16) & 1u)) >> 16;   // round-to-nearest-even
    return (u16)r;
}
__device__ __forceinline__ float blo(u32 w) { return __uint_as_float(w << 16); }
__device__ __forceinline__ float bhi(u32 w) { return __uint_as_float(w & 0xffff0000u); }

// ---------------- prep: MtB | w0s/w0d | edge->bin fill (r16 layout) ----------------
__global__ void k_prep(const float* __restrict__ Wq, const float* __restrict__ Wk, u16* __restrict__ MtB,
                       const float* __restrict__ W0,
                       const float* __restrict__ asrc, const float* __restrict__ adst,
                       float* __restrict__ w0s, float* __restrict__ w0d,
                       const int* __restrict__ src, const int* __restrict__ dst,
                       int* __restrict__ cnt, int* __restrict__ cs, int E) {
    int b = blockIdx.x, t = threadIdx.x;
    if (b < 64) {
        int id = b * 256 + t;                  // [0, 16384)
        int bcol = id >> 7, a = id & 127;
        const float* wqr = Wq + a * 128;
        const float* wkr = Wk + bcol * 128;
        float dt = 0.f;
        for (int j = 0; j < 128; j += 4) {
            float4 q4 = *reinterpret_cast<const float4*>(wqr + j);
            float4 k4 = *reinterpret_cast<const float4*>(wkr + j);
            dt += q4.x * k4.x + q4.y * k4.y + q4.z * k4.z + q4.w * k4.w;
        }
        MtB[id] = f2b(dt * 0.08838834764831845f);
    } else if (b == 64) {
        int k = t & 127;
        const float* av = (t < 128) ? asrc : adst;
        const float* wr = W0 + k * 128;
        float dt = 0.f;
        for (int j = 0; j < 128; j += 4) {
            float4 w4 = *reinterpret_cast<const float4*>(wr + j);
            float4 a4 = *reinterpret_cast<const float4*>(av + j);
            dt += w4.x * a4.x + w4.y * a4.y + w4.z * a4.z + w4.w * a4.w;
        }
        if (t < 128) w0s[k] = dt; else w0d[k] = dt;
    } else {
        int e = (b - 65) * 256 + t;
        if (e < E) {
            int d = dst[e];
            int slot = atomicAdd(&cnt[d], 1);
            if (slot < 32) cs[(size_t)d * 32 + slot] = src[e];
        }
    }
}

// ---------------- pre-GEMM: fp32 X -> Xb (bf16) + Q' = X@M + a_s/a_d ; + Wf prep blocks ----
__global__ __launch_bounds__(512) void k_pre(const float* __restrict__ X, u16* __restrict__ Xb,
                                             const u16* __restrict__ MtB,
                                             const float* __restrict__ w0s, const float* __restrict__ w0d,
                                             const float* __restrict__ W0, const float* __restrict__ Wv,
                                             const float* __restrict__ Wr, u16* __restrict__ Wf,
                                             u16* __restrict__ Qp, float* __restrict__ a_s,
                                             float* __restrict__ a_d, int N, int nxb) {
    const int tid = threadIdx.x;
    if ((int)blockIdx.x >= nxb) {
        // Wf fragment order: chunk = ((g*4+w)*2+p)*4+kc ; lane l elem i:
        //   col = w*32 + 2*(l&15) + p ; k = kc*32 + (l>>4)*8 + i ; value = W_g[k][col]
        int id = ((int)blockIdx.x - nxb) * 512 + tid;   // [0, 49152)
        int i = id & 7, l = (id >> 3) & 63, chunk = id >> 9;
        int kc = chunk & 3, p = (chunk >> 2) & 1, wv = (chunk >> 3) & 3, g = chunk >> 5;
        int col = wv * 32 + 2 * (l & 15) + p;
        int k = kc * 32 + (l >> 4) * 8 + i;
        const float* W = g == 0 ? W0 : g == 1 ? Wv : Wr;
        Wf[id] = f2b(W[k * 128 + col]);
        return;
    }

    __shared__ u16 Bs[128][136];
    const int row0 = blockIdx.x * 128;

    for (int c = tid; c < 128 * 16; c += 512) {
        int r = c >> 4, col8 = (c & 15) * 8;
        *reinterpret_cast<short8*>(&Bs[r][col8]) =
            *reinterpret_cast<const short8*>(MtB + r * 128 + col8);
    }

    const int wid = tid >> 6, lane = tid & 63;
    const int l15 = lane & 15;
    const int kg = (lane >> 4) * 8;
    const int arow = row0 + wid * 16 + l15;

    short8 af[4];
    if (arow < N) {
        const float* xp = X + (size_t)arow * 128 + kg;
        u16* xbp = Xb + (size_t)arow * 128 + kg;
#pragma unroll
        for (int kc = 0; kc < 4; kc++) {
            float4 f0 = *reinterpret_cast<const float4*>(xp + kc * 32);
            float4 f1 = *reinterpret_cast<const float4*>(xp + kc * 32 + 4);
            short8 vv;
            vv[0] = (short)f2b(f0.x); vv[1] = (short)f2b(f0.y);
            vv[2] = (short)f2b(f0.z); vv[3] = (short)f2b(f0.w);
            vv[4] = (short)f2b(f1.x); vv[5] = (short)f2b(f1.y);
            vv[6] = (short)f2b(f1.z); vv[7] = (short)f2b(f1.w);
            af[kc] = vv;
            *reinterpret_cast<short8*>(xbp + kc * 32) = vv;
        }
    } else {
        short8 z = {0, 0, 0, 0, 0, 0, 0, 0};
#pragma unroll
        for (int kc = 0; kc < 4; kc++) af[kc] = z;
    }
    __syncthreads();

    float ps = 0.f, pd = 0.f;
#pragma unroll
    for (int kc = 0; kc < 4; kc++) {
        float4 s0 = *reinterpret_cast<const float4*>(w0s + kc * 32 + kg);
        float4 s1 = *reinterpret_cast<const float4*>(w0s + kc * 32 + kg + 4);
        float4 d0 = *reinterpret_cast<const float4*>(w0d + kc * 32 + kg);
        float4 d1 = *reinterpret_cast<const float4*>(w0d + kc * 32 + kg + 4);
        float xs[8];
#pragma unroll
        for (int i = 0; i < 8; i++) xs[i] = __uint_as_float(((u32)(u16)af[kc][i]) << 16);
        ps += xs[0] * s0.x + xs[1] * s0.y + xs[2] * s0.z + xs[3] * s0.w
            + xs[4] * s1.x + xs[5] * s1.y + xs[6] * s1.z + xs[7] * s1.w;
        pd += xs[0] * d0.x + xs[1] * d0.y + xs[2] * d0.z + xs[3] * d0.w
            + xs[4] * d1.x + xs[5] * d1.y + xs[6] * d1.z + xs[7] * d1.w;
    }
    ps += __shfl_xor(ps, 16); ps += __shfl_xor(ps, 32);
    pd += __shfl_xor(pd, 16); pd += __shfl_xor(pd, 32);
    if (lane < 16 && arow < N) { a_s[arow] = ps; a_d[arow] = pd; }

    const int rbase = row0 + wid * 16 + ((lane >> 4) << 2);

#pragma unroll
    for (int c2 = 0; c2 < 4; c2++) {
        const int col0 = c2 * 32 + 2 * l15;
        f32x4 acc0 = {0.f, 0.f, 0.f, 0.f};
        f32x4 acc1 = {0.f, 0.f, 0.f, 0.f};
#pragma unroll
        for (int kc = 0; kc < 4; kc++) {
            short8 bf0 = *reinterpret_cast<const short8*>(&Bs[col0][kc * 32 + kg]);
            short8 bf1 = *reinterpret_cast<const short8*>(&Bs[col0 + 1][kc * 32 + kg]);
            acc0 = __builtin_amdgcn_mfma_f32_16x16x32_bf16(af[kc], bf0, acc0, 0, 0, 0);
            acc1 = __builtin_amdgcn_mfma_f32_16x16x32_bf16(af[kc], bf1, acc1, 0, 0, 0);
        }
#pragma unroll
        for (int r = 0; r < 4; r++) {
            int grow = rbase + r;
            if (grow < N) {
                u32 pk = (u32)f2b(acc0[r]) | ((u32)f2b(acc1[r]) << 16);
                *reinterpret_cast<u32*>(Qp + (size_t)grow * 128 + col0) = pk;
            }
        }
    }
}

// ---------------- fused edge + post (r16 structure; phase A unrolled x2) ----------------
// 16 nodes/block, one MFMA tile (r13/r14/r21 multi-node variants all lost to register/
// occupancy rent — this structure is the local optimum). Phase A main loop processes two
// edges per iteration: two independent Xb gathers in flight per group.
// No max-subtraction (validated r1-r21).
__global__ __launch_bounds__(256) void k_edge(const int* __restrict__ cnt, const int* __restrict__ cs,
                                              const u16* __restrict__ Xb, const u16* __restrict__ Qp,
                                              const float* __restrict__ a_s, const float* __restrict__ a_d,
                                              const u16* __restrict__ Wf, const float* __restrict__ bias,
                                              float* __restrict__ out,
                                              const int* __restrict__ srcp, const int* __restrict__ dstp,
                                              int E, int N) {
    __shared__ u16 As[3][16][136];   // [ax|bx|x][node][col] (+8 pad)
    __shared__ float ssp[4][16];     // per-wave row-norm partials
    const int tid = threadIdx.x;
    const int node0 = blockIdx.x * 16;
    const int g16 = tid >> 4;
    const int n = node0 + g16;
    const int l = tid & 15;
    const int l8 = l * 8;

    // ---------------- phase A ----------------
    if (n < N) {
        u32x4 qv = *reinterpret_cast<const u32x4*>(Qp + (size_t)n * 128 + l8);
        short8 selfx = *reinterpret_cast<const short8*>(Xb + ((size_t)n << 7) + l8);
        float qf[8];
#pragma unroll
        for (int i = 0; i < 4; i++) { qf[2 * i] = blo(qv[i]); qf[2 * i + 1] = bhi(qv[i]); }

        const int deg = cnt[n];
        const int binb = n * 32;
        const float adn = a_d[n];

        float axr[8] = {0.f, 0.f, 0.f, 0.f, 0.f, 0.f, 0.f, 0.f};
        float bxr[8] = {0.f, 0.f, 0.f, 0.f, 0.f, 0.f, 0.f, 0.f};
        float zg = 0.f, zt = 0.f;

        if (deg <= 32) {
            const int m = deg < 16 ? deg : 16;
            int sx_l = 0;
            float wg_l = 0.f;
            if (l < m) {
                int s = cs[binb + l];
                float gl = a_s[s] + adn;
                gl = gl >= 0.f ? gl : 0.2f * gl;  // LeakyReLU(0.2)
                wg_l = __expf(gl);
                sx_l = s << 7;
            }
            int j = 0;
            for (; j + 2 <= m; j += 2) {          // two edges in flight
                int ex0 = __shfl(sx_l, j, 16);
                int ex1 = __shfl(sx_l, j + 1, 16);
                float wg0 = __shfl(wg_l, j, 16);
                float wg1 = __shfl(wg_l, j + 1, 16);
                u32x4 xv0 = *reinterpret_cast<const u32x4*>(Xb + ex0 + l8);
                u32x4 xv1 = *reinterpret_cast<const u32x4*>(Xb + ex1 + l8);

                float d0 = 0.f, d1 = 0.f;
#pragma unroll
                for (int i = 0; i < 4; i++) {
                    d0 = fmaf(qf[2 * i], blo(xv0[i]), d0);
                    d0 = fmaf(qf[2 * i + 1], bhi(xv0[i]), d0);
                    d1 = fmaf(qf[2 * i], blo(xv1[i]), d1);
                    d1 = fmaf(qf[2 * i + 1], bhi(xv1[i]), d1);
                }
#pragma unroll
                for (int off = 1; off < 16; off <<= 1) {
                    d0 += __shfl_xor(d0, off);
                    d1 += __shfl_xor(d1, off);
                }
                float wt0 = __expf(d0), wt1 = __expf(d1);   // 1/sqrt(D) folded into M

#pragma unroll
                for (int i = 0; i < 4; i++) {
                    float x0 = blo(xv0[i]), x1 = bhi(xv0[i]);
                    float y0 = blo(xv1[i]), y1 = bhi(xv1[i]);
                    axr[2 * i]     = fmaf(wg0, x0, fmaf(wg1, y0, axr[2 * i]));
                    axr[2 * i + 1] = fmaf(wg0, x1, fmaf(wg1, y1, axr[2 * i + 1]));
                    bxr[2 * i]     = fmaf(wt0, x0, fmaf(wt1, y0, bxr[2 * i]));
                    bxr[2 * i + 1] = fmaf(wt0, x1, fmaf(wt1, y1, bxr[2 * i + 1]));
                }
                zg += wg0 + wg1;
                zt += wt0 + wt1;
            }
            if (j < m) {
                int ex0 = __shfl(sx_l, j, 16);
                float wg0 = __shfl(wg_l, j, 16);
                u32x4 xv0 = *reinterpret_cast<const u32x4*>(Xb + ex0 + l8);
                float d0 = 0.f;
#pragma unroll
                for (int i = 0; i < 4; i++) {
                    d0 = fmaf(qf[2 * i], blo(xv0[i]), d0);
                    d0 = fmaf(qf[2 * i + 1], bhi(xv0[i]), d0);
                }
#pragma unroll
                for (int off = 1; off < 16; off <<= 1) d0 += __shfl_xor(d0, off);
                float wt0 = __expf(d0);
#pragma unroll
                for (int i = 0; i < 4; i++) {
                    float x0 = blo(xv0[i]), x1 = bhi(xv0[i]);
                    axr[2 * i]     = fmaf(wg0, x0, axr[2 * i]);
                    axr[2 * i + 1] = fmaf(wg0, x1, axr[2 * i + 1]);
                    bxr[2 * i]     = fmaf(wt0, x0, bxr[2 * i]);
                    bxr[2 * i + 1] = fmaf(wt0, x1, bxr[2 * i + 1]);
                }
                zg += wg0;
                zt += wt0;
            }
            for (int p = 16; p < deg; p++) {      // 16 < deg <= 32
                int s = cs[binb + p];
                float gl = a_s[s] + adn;
                gl = gl >= 0.f ? gl : 0.2f * gl;
                float wg0 = __expf(gl);
                u32x4 xv0 = *reinterpret_cast<const u32x4*>(Xb + (s << 7) + l8);
                float d0 = 0.f;
#pragma unroll
                for (int i = 0; i < 4; i++) {
                    d0 = fmaf(qf[2 * i], blo(xv0[i]), d0);
                    d0 = fmaf(qf[2 * i + 1], bhi(xv0[i]), d0);
                }
#pragma unroll
                for (int off = 1; off < 16; off <<= 1) d0 += __shfl_xor(d0, off);
                float wt0 = __expf(d0);
#pragma unroll
                for (int i = 0; i < 4; i++) {
                    float x0 = blo(xv0[i]), x1 = bhi(xv0[i]);
                    axr[2 * i]     = fmaf(wg0, x0, axr[2 * i]);
                    axr[2 * i + 1] = fmaf(wg0, x1, axr[2 * i + 1]);
                    bxr[2 * i]     = fmaf(wt0, x0, bxr[2 * i]);
                    bxr[2 * i + 1] = fmaf(wt0, x1, bxr[2 * i + 1]);
                }
                zg += wg0;
                zt += wt0;
            }
        } else {
            // correctness insurance (deg > 32, ~P=1e-15/node): full edge rescan
            for (int e = 0; e < E; e++) {
                if (dstp[e] == n) {
                    int s = srcp[e];
                    float gl = a_s[s] + adn;
                    gl = gl >= 0.f ? gl : 0.2f * gl;
                    float wg0 = __expf(gl);
                    u32x4 xv0 = *reinterpret_cast<const u32x4*>(Xb + (s << 7) + l8);
                    float d0 = 0.f;
#pragma unroll
                    for (int i = 0; i < 4; i++) {
                        d0 = fmaf(qf[2 * i], blo(xv0[i]), d0);
                        d0 = fmaf(qf[2 * i + 1], bhi(xv0[i]), d0);
                    }
#pragma unroll
                    for (int off = 1; off < 16; off <<= 1) d0 += __shfl_xor(d0, off);
                    float wt0 = __expf(d0);
#pragma unroll
                    for (int i = 0; i < 4; i++) {
                        float x0 = blo(xv0[i]), x1 = bhi(xv0[i]);
                        axr[2 * i]     = fmaf(wg0, x0, axr[2 * i]);
                        axr[2 * i + 1] = fmaf(wg0, x1, axr[2 * i + 1]);
                        bxr[2 * i]     = fmaf(wt0, x0, bxr[2 * i]);
                        bxr[2 * i + 1] = fmaf(wt0, x1, bxr[2 * i + 1]);
                    }
                    zg += wg0;
                    zt += wt0;
                }
            }
        }

        float ig = 1.f / (zg + 1e-16f), it = 1.f / (zt + 1e-16f);
        short8 pax, pbx;
#pragma unroll
        for (int i = 0; i < 8; i++) {
            pax[i] = (short)f2b(axr[i] * ig);
            pbx[i] = (short)f2b(bxr[i] * it);
        }
        *reinterpret_cast<short8*>(&As[0][g16][l8]) = pax;
        *reinterpret_cast<short8*>(&As[1][g16][l8]) = pbx;
        *reinterpret_cast<short8*>(&As[2][g16][l8]) = selfx;
    } else {
        short8 z = {0, 0, 0, 0, 0, 0, 0, 0};
        *reinterpret_cast<short8*>(&As[0][g16][l8]) = z;
        *reinterpret_cast<short8*>(&As[1][g16][l8]) = z;
        *reinterpret_cast<short8*>(&As[2][g16][l8]) = z;
    }
    __syncthreads();

    // ---------------- phase B ----------------
    const int w = tid >> 6;          // wave id: cols [w*32, w*32+32)
    const int lane = tid & 63;
    const int l15 = lane & 15;
    const int q = lane >> 4;
    const int kg = q * 8;

    f32x4 aG0 = {0.f, 0.f, 0.f, 0.f}, aG1 = {0.f, 0.f, 0.f, 0.f};
    f32x4 aD0 = {0.f, 0.f, 0.f, 0.f}, aD1 = {0.f, 0.f, 0.f, 0.f};

#pragma unroll
    for (int g = 0; g < 3; g++) {
        short8 af[4];
#pragma unroll
        for (int kc = 0; kc < 4; kc++)
            af[kc] = *reinterpret_cast<const short8*>(&As[g][l15][kc * 32 + kg]);
        const u16* wfg = Wf + (((g * 4 + w) * 2) << 11);
#pragma unroll
        for (int kc = 0; kc < 4; kc++) {
            short8 bf0 = *reinterpret_cast<const short8*>(wfg + kc * 512 + lane * 8);
            short8 bf1 = *reinterpret_cast<const short8*>(wfg + (4 + kc) * 512 + lane * 8);
            if (g == 0) {
                aG0 = __builtin_amdgcn_mfma_f32_16x16x32_bf16(af[kc], bf0, aG0, 0, 0, 0);
                aG1 = __builtin_amdgcn_mfma_f32_16x16x32_bf16(af[kc], bf1, aG1, 0, 0, 0);
            } else {
                aD0 = __builtin_amdgcn_mfma_f32_16x16x32_bf16(af[kc], bf0, aD0, 0, 0, 0);
                aD1 = __builtin_amdgcn_mfma_f32_16x16x32_bf16(af[kc], bf1, aD1, 0, 0, 0);
            }
        }
    }

    // epilogue: relu+bias, add, cross-wave row L2-norm, store
    const int col0 = w * 32 + 2 * l15;
    float2 bb = *reinterpret_cast<const float2*>(bias + col0);
    float o0[4], o1[4], ssr[4];
#pragma unroll
    for (int r = 0; r < 4; r++) {
        float g0 = fmaxf(aG0[r] + bb.x, 0.f);
        float g1 = fmaxf(aG1[r] + bb.y, 0.f);
        o0[r] = g0 + aD0[r];
        o1[r] = g1 + aD1[r];
        ssr[r] = o0[r] * o0[r] + o1[r] * o1[r];
    }
#pragma unroll
    for (int off = 1; off < 16; off <<= 1) {
#pragma unroll
        for (int r = 0; r < 4; r++) ssr[r] += __shfl_xor(ssr[r], off);
    }
    if (l15 == 0) {
#pragma unroll
        for (int r = 0; r < 4; r++) ssp[w][q * 4 + r] = ssr[r];
    }
    __syncthreads();
#pragma unroll
    for (int r = 0; r < 4; r++) {
        int row = q * 4 + r;
        float tot = ssp[0][row] + ssp[1][row] + ssp[2][row] + ssp[3][row];
        float inv = 1.f / fmaxf(sqrtf(tot), 1e-12f);
        int grow = node0 + row;
        if (grow < N) {
            float2 ov = {o0[r] * inv, o1[r] * inv};
            *reinterpret_cast<float2*>(out + (size_t)grow * 128 + col0) = ov;
        }
    }
}

// ---------------- host launcher ----------------
extern "C" void kernel_launch(void* const* d_in, const int* in_sizes, int n_in,
                              void* d_out, int out_size, void* d_ws, size_t ws_size,
                              hipStream_t stream) {
    const int* edge = (const int*)d_in[1];
    const float* emb = (const float*)d_in[2];
    const float* gat_W = (const float*)d_in[3];
    const float* a_src = (const float*)d_in[4];
    const float* a_dst = (const float*)d_in[5];
    const float* bias = (const float*)d_in[6];
    const float* Wq = (const float*)d_in[7];
    const float* Wk = (const float*)d_in[8];
    const float* Wv = (const float*)d_in[9];
    const float* Wr = (const float*)d_in[10];

    const int E = in_sizes[1] / 2;
    const int N = in_sizes[2] / 128;
    const int* src = edge;
    const int* dst = edge + E;
    float* out = (float*)d_out;

    char* w = (char*)d_ws;
    auto alloc = [&](size_t bytes) -> char* {
        char* p = w;
        w += (bytes + 255) & ~(size_t)255;
        return p;
    };
    u16* Xb  = (u16*)alloc((size_t)N * 128 * 2);
    u16* Qp  = (u16*)alloc((size_t)N * 128 * 2);
    u16* MtB = (u16*)alloc(128 * 128 * 2);
    u16* Wf  = (u16*)alloc(3 * 128 * 128 * 2);
    float* w0s = (float*)alloc(128 * 4);
    float* w0d = (float*)alloc(128 * 4);
    float* a_s = (float*)alloc((size_t)N * 4);
    float* a_d = (float*)alloc((size_t)N * 4);
    int* cnt  = (int*)alloc((size_t)N * 4);
    int* cs   = (int*)alloc((size_t)N * 32 * 4);   // fixed-capacity bins (12.8 MB)

    const int nhist = (E + 255) / 256;
    const int nxb = (N + 127) / 128;

    hipMemsetAsync(cnt, 0, (size_t)N * 4, stream);
    k_prep<<<65 + nhist, 256, 0, stream>>>(Wq, Wk, MtB, gat_W, a_src, a_dst, w0s, w0d,
                                           src, dst, cnt, cs, E);
    k_pre<<<nxb + 96, 512, 0, stream>>>(emb, Xb, MtB, w0s, w0d, gat_W, Wv, Wr, Wf,
                                        Qp, a_s, a_d, N, nxb);
    k_edge<<<(N + 15) / 16, 256, 0, stream>>>(cnt, cs, Xb, Qp, a_s, a_d, Wf, bias, out,
                                              src, dst, E, N);
}